// Round 17
// baseline (255.362 us; speedup 1.0000x reference)
//
#include <hip/hip_runtime.h>
#include <hip/hip_fp16.h>

#define NT      250000
#define NN      20000
#define RP      8
#define EMB     64
#define NCLS    16
#define NRELS   64
#define REDB    64
#define KMAX    140000    // max segment id + 1 (19999*7 = 139993)
#define GEMVB   977       // blocks for gemv part
#define RPB     79        // blocks for rowptr part
#define HIB     977       // blocks for hist part
#define OIB     1250      // blocks for out=bias2 init (1250*256 = 320000 exactly)

// ---------------- A (fused): GEMV + softmax | rowptr | histogram | out-init ----------------
__global__ __launch_bounds__(256) void k_gemv(
    const float* __restrict__ rm,
    const float* __restrict__ W1, const float* __restrict__ b1,
    const float* __restrict__ W2, const float* __restrict__ b2,
    float* __restrict__ l1, float* __restrict__ l2,
    const int* __restrict__ hrow, int* __restrict__ rowptr,
    const int* __restrict__ vcol, int* __restrict__ cnt,
    float* __restrict__ out, const float* __restrict__ bias2)
{
    __shared__ float tile[256 * 20];
    int bid = blockIdx.x;
    if (bid >= GEMVB) {
        int b = bid - GEMVB;
        if (b < RPB) {                    // CSR offsets via binary search
            int i = b * 256 + threadIdx.x;
            if (i > NN) return;
            int lo = 0, hi = NT;
            while (lo < hi) { int mid = (lo + hi) >> 1; if (hrow[mid] < i) lo = mid + 1; else hi = mid; }
            rowptr[i] = lo;
        } else if (b < RPB + HIB) {       // vcol histogram
            int p = (b - RPB) * 256 + threadIdx.x;
            if (p < NT) atomicAdd(&cnt[vcol[p]], 1);
        } else {                          // out = bias2 broadcast
            int i = (b - RPB - HIB) * 256 + threadIdx.x;
            if (i < NN * NCLS) out[i] = bias2[i & (NCLS - 1)];
        }
        return;
    }
    int t = threadIdx.x;
    int base = bid * 256;
    float a1[8], a2[8];
#pragma unroll
    for (int r = 0; r < 8; ++r) { a1[r] = b1[r]; a2[r] = b2[r]; }

#pragma unroll 1
    for (int kc = 0; kc < 4; ++kc) {
        __syncthreads();
#pragma unroll
        for (int q = 0; q < 4; ++q) {
            int i = q * 256 + t;
            int pl = i >> 2, j4 = i & 3;
            int p = base + pl;
            float4 v = make_float4(0.f, 0.f, 0.f, 0.f);
            if (p < NT) v = reinterpret_cast<const float4*>(rm)[(size_t)p * 16 + kc * 4 + j4];
            *reinterpret_cast<float4*>(&tile[pl * 20 + j4 * 4]) = v;
        }
        __syncthreads();
        float xr[16];
#pragma unroll
        for (int j4 = 0; j4 < 4; ++j4) {
            float4 v = *reinterpret_cast<const float4*>(&tile[t * 20 + j4 * 4]);
            xr[j4 * 4 + 0] = v.x; xr[j4 * 4 + 1] = v.y;
            xr[j4 * 4 + 2] = v.z; xr[j4 * 4 + 3] = v.w;
        }
#pragma unroll
        for (int kk = 0; kk < 16; ++kk) {
            float x = xr[kk];
            int k = kc * 16 + kk;
#pragma unroll
            for (int r = 0; r < 8; ++r) {
                a1[r] = fmaf(x, W1[k * 8 + r], a1[r]);
                a2[r] = fmaf(x, W2[k * 8 + r], a2[r]);
            }
        }
    }
    int p = base + t;
    if (p >= NT) return;
    float mx = a2[0];
#pragma unroll
    for (int r = 1; r < 8; ++r) mx = fmaxf(mx, a2[r]);
    float sm = 0.f;
#pragma unroll
    for (int r = 0; r < 8; ++r) { a2[r] = __expf(a2[r] - mx); sm += a2[r]; }
    float inv = 1.0f / sm;
#pragma unroll
    for (int r = 0; r < 8; ++r) a2[r] *= inv;
    float4* o1 = reinterpret_cast<float4*>(l1 + (size_t)p * 8);
    float4* o2 = reinterpret_cast<float4*>(l2 + (size_t)p * 8);
    o1[0] = make_float4(a1[0], a1[1], a1[2], a1[3]);
    o1[1] = make_float4(a1[4], a1[5], a1[6], a1[7]);
    o2[0] = make_float4(a2[0], a2[1], a2[2], a2[3]);
    o2[1] = make_float4(a2[4], a2[5], a2[6], a2[7]);
}

__global__ __launch_bounds__(1024) void k_scan(
    const int* __restrict__ cnt, int* __restrict__ cstart, int* __restrict__ cnt2)
{
    __shared__ int part[1024];
    int t = threadIdx.x;
    int base = t * 20;
    int local[20];
    int s = 0;
#pragma unroll
    for (int i = 0; i < 20; ++i) {
        int idx = base + i;
        int c = (idx < NN) ? cnt[idx] : 0;
        local[i] = s;
        s += c;
    }
    part[t] = s;
    __syncthreads();
    for (int off = 1; off < 1024; off <<= 1) {
        int v = (t >= off) ? part[t - off] : 0;
        __syncthreads();
        part[t] += v;
        __syncthreads();
    }
    int ebase = t ? part[t - 1] : 0;
#pragma unroll
    for (int i = 0; i < 20; ++i) {
        int idx = base + i;
        if (idx < NN) { cstart[idx] = ebase + local[i]; cnt2[idx] = ebase + local[i]; }
    }
    if (t == 1023) cstart[NN] = part[1023];
}

__global__ __launch_bounds__(256) void k_pos(
    const int* __restrict__ vcol, int* __restrict__ cnt2, int* __restrict__ cscidx)
{
    int p = blockIdx.x * blockDim.x + threadIdx.x;
    if (p >= NT) return;
    int o = vcol[p];
    int slot = atomicAdd(&cnt2[o], 1);
    cscidx[slot] = p;
}

// ---------------- colsum: wave per o (r=1..7) + REDB streaming blocks (r=0 -> colsum[0]) ----------------
__global__ __launch_bounds__(256) void k_colsum(
    const float* __restrict__ l1, const int* __restrict__ cstart,
    const int* __restrict__ cscidx, float* __restrict__ colsum)
{
    int bid = blockIdx.x;
    if (bid < NN / 4) {
        int o = bid * 4 + (threadIdx.x >> 6);
        int lane = threadIdx.x & 63;
        int qb = cstart[o], qe = cstart[o + 1];
        if (qb == qe) return;
        int j = lane >> 3, r = lane & 7;
        float sum = 0.f;
        for (int q0 = qb; q0 < qe; q0 += 8) {
            int q = q0 + j;
            if (q < qe) sum += l1[(size_t)cscidx[q] * 8 + r];
        }
        sum += __shfl_xor(sum, 8, 64);
        sum += __shfl_xor(sum, 16, 64);
        sum += __shfl_xor(sum, 32, 64);   // lanes 0..7 hold per-r totals
        if (lane >= 1 && lane < 8) atomicAdd(&colsum[o * lane], sum);
    } else {
        int b2 = bid - NN / 4;
        float s = 0.f;
        for (int i = b2 * 256 + threadIdx.x; i < NT; i += REDB * 256) s += l1[(size_t)i * 8];
        __shared__ float red[256];
        red[threadIdx.x] = s;
        __syncthreads();
        for (int off = 128; off > 0; off >>= 1) {
            if (threadIdx.x < off) red[threadIdx.x] += red[threadIdx.x + off];
            __syncthreads();
        }
        if (threadIdx.x == 0) atomicAdd(&colsum[0], red[0]);
    }
}

// ---------------- C1: per-object contributions -> atomic fp32 h_acc (no contrib buffer) ----------------
__global__ __launch_bounds__(256) void k_hacc(
    const float* __restrict__ l1, const float* __restrict__ colsum,
    const int* __restrict__ cstart, const int* __restrict__ cscidx,
    const int* __restrict__ hrow, const float* __restrict__ w1,
    float* __restrict__ h_acc)
{
    int o = (int)((blockIdx.x * blockDim.x + threadIdx.x) >> 6);
    int lane = threadIdx.x & 63;
    if (o >= NN) return;
    int qb = cstart[o], qe = cstart[o + 1];
    if (qb == qe) return;
    float y[8];
    y[0] = w1[lane] / colsum[0];
#pragma unroll
    for (int r = 1; r < 8; ++r) {
        int seg = o * r;
        y[r] = w1[(size_t)seg * EMB + lane] / colsum[seg];
    }
    int q = qb;
    for (; q + 3 < qe; q += 4) {          // 4 l1 gathers + 4 hrow gathers in flight
        int p0 = cscidx[q], p1 = cscidx[q + 1], p2 = cscidx[q + 2], p3 = cscidx[q + 3];
        int s0 = hrow[p0], s1 = hrow[p1], s2 = hrow[p2], s3 = hrow[p3];
        const float4* a4 = reinterpret_cast<const float4*>(l1 + (size_t)p0 * 8);
        const float4* b4 = reinterpret_cast<const float4*>(l1 + (size_t)p1 * 8);
        const float4* c4 = reinterpret_cast<const float4*>(l1 + (size_t)p2 * 8);
        const float4* d4 = reinterpret_cast<const float4*>(l1 + (size_t)p3 * 8);
        float4 A = a4[0], B = a4[1], C = b4[0], D = b4[1];
        float4 E = c4[0], F = c4[1], G = d4[0], H = d4[1];
        float v0 = A.x * y[0];
        v0 = fmaf(A.y, y[1], v0); v0 = fmaf(A.z, y[2], v0); v0 = fmaf(A.w, y[3], v0);
        v0 = fmaf(B.x, y[4], v0); v0 = fmaf(B.y, y[5], v0);
        v0 = fmaf(B.z, y[6], v0); v0 = fmaf(B.w, y[7], v0);
        float v1 = C.x * y[0];
        v1 = fmaf(C.y, y[1], v1); v1 = fmaf(C.z, y[2], v1); v1 = fmaf(C.w, y[3], v1);
        v1 = fmaf(D.x, y[4], v1); v1 = fmaf(D.y, y[5], v1);
        v1 = fmaf(D.z, y[6], v1); v1 = fmaf(D.w, y[7], v1);
        float v2 = E.x * y[0];
        v2 = fmaf(E.y, y[1], v2); v2 = fmaf(E.z, y[2], v2); v2 = fmaf(E.w, y[3], v2);
        v2 = fmaf(F.x, y[4], v2); v2 = fmaf(F.y, y[5], v2);
        v2 = fmaf(F.z, y[6], v2); v2 = fmaf(F.w, y[7], v2);
        float v3 = G.x * y[0];
        v3 = fmaf(G.y, y[1], v3); v3 = fmaf(G.z, y[2], v3); v3 = fmaf(G.w, y[3], v3);
        v3 = fmaf(H.x, y[4], v3); v3 = fmaf(H.y, y[5], v3);
        v3 = fmaf(H.z, y[6], v3); v3 = fmaf(H.w, y[7], v3);
        atomicAdd(&h_acc[(size_t)s0 * EMB + lane], v0);
        atomicAdd(&h_acc[(size_t)s1 * EMB + lane], v1);
        atomicAdd(&h_acc[(size_t)s2 * EMB + lane], v2);
        atomicAdd(&h_acc[(size_t)s3 * EMB + lane], v3);
    }
    for (; q < qe; ++q) {
        int p0 = cscidx[q];
        int s0 = hrow[p0];
        const float4* a4 = reinterpret_cast<const float4*>(l1 + (size_t)p0 * 8);
        float4 A = a4[0], B = a4[1];
        float v0 = A.x * y[0];
        v0 = fmaf(A.y, y[1], v0); v0 = fmaf(A.z, y[2], v0); v0 = fmaf(A.w, y[3], v0);
        v0 = fmaf(B.x, y[4], v0); v0 = fmaf(B.y, y[5], v0);
        v0 = fmaf(B.z, y[6], v0); v0 = fmaf(B.w, y[7], v0);
        atomicAdd(&h_acc[(size_t)s0 * EMB + lane], v0);
    }
}

// ---------------- C2: h = fp16(relu(h_acc + bias1)) + rowsum pre-pass ----------------
__global__ __launch_bounds__(256) void k_h(
    const float* __restrict__ h_acc, const float* __restrict__ l2,
    const int* __restrict__ rowptr, const float* __restrict__ bias1,
    __half* __restrict__ h, float* __restrict__ rowsum, float* __restrict__ rs0part)
{
    int s = (int)((blockIdx.x * blockDim.x + threadIdx.x) >> 6);
    int lane = threadIdx.x & 63;
    if (s >= NN) return;
    int pb = rowptr[s], pe = rowptr[s + 1];
    float acc = h_acc[(size_t)s * EMB + lane];
    h[(size_t)s * EMB + lane] = __float2half(fmaxf(acc + bias1[lane], 0.f));

    float psum = 0.f;
    for (int p0 = pb + (lane >> 3); p0 < pe; p0 += 8)
        psum += l2[(size_t)p0 * 8 + (lane & 7)];
    psum += __shfl_xor(psum, 8, 64);
    psum += __shfl_xor(psum, 16, 64);
    psum += __shfl_xor(psum, 32, 64);
    if (s == 0) {
        float tt = psum;
        tt += __shfl_xor(tt, 1, 64);
        tt += __shfl_xor(tt, 2, 64);
        tt += __shfl_xor(tt, 4, 64);
        if (lane == 0) rs0part[0] = tt;
    } else {
        if (lane == 0) rs0part[s] = psum;
        else if (lane < 8) atomicAdd(&rowsum[s * lane], psum);
    }
}

// ---------------- D+E fused: single wave per s, unroll-4, fast-rcp rowsum divides ----------------
__global__ __launch_bounds__(256) void k_l2out(
    const float* __restrict__ l2, const int* __restrict__ rowptr,
    const int* __restrict__ vcol, const __half* __restrict__ h,
    const float* __restrict__ rowsum, const float* __restrict__ w2,
    float* __restrict__ out, float* __restrict__ Abuf0)
{
    int s = (int)((blockIdx.x * blockDim.x + threadIdx.x) >> 6);
    int lane = threadIdx.x & 63;
    if (s >= NN) return;
    int pb = rowptr[s], pe = rowptr[s + 1];
    float sc[8];
#pragma unroll
    for (int rr = 1; rr < 8; ++rr)
        sc[rr] = (s > 0) ? __builtin_amdgcn_rcpf(fmaxf(rowsum[s * rr], 1e-6f)) : 0.f;
    float acc[8];
#pragma unroll
    for (int r = 0; r < 8; ++r) acc[r] = 0.f;
    int p = pb;
    for (; p + 3 < pe; p += 4) {            // four h gathers in flight
        int o0 = vcol[p], o1 = vcol[p + 1], o2 = vcol[p + 2], o3 = vcol[p + 3];
        float hv0 = __half2float(h[(size_t)o0 * EMB + lane]);
        float hv1 = __half2float(h[(size_t)o1 * EMB + lane]);
        float hv2 = __half2float(h[(size_t)o2 * EMB + lane]);
        float hv3 = __half2float(h[(size_t)o3 * EMB + lane]);
        const float4* q4 = reinterpret_cast<const float4*>(l2 + (size_t)p * 8);
        float4 A = q4[0], B = q4[1], C = q4[2], D = q4[3];
        float4 E = q4[4], F = q4[5], G = q4[6], H = q4[7];
        acc[0] = fmaf(A.x, hv0, fmaf(C.x, hv1, fmaf(E.x, hv2, fmaf(G.x, hv3, acc[0]))));
        acc[1] = fmaf(A.y, hv0, fmaf(C.y, hv1, fmaf(E.y, hv2, fmaf(G.y, hv3, acc[1]))));
        acc[2] = fmaf(A.z, hv0, fmaf(C.z, hv1, fmaf(E.z, hv2, fmaf(G.z, hv3, acc[2]))));
        acc[3] = fmaf(A.w, hv0, fmaf(C.w, hv1, fmaf(E.w, hv2, fmaf(G.w, hv3, acc[3]))));
        acc[4] = fmaf(B.x, hv0, fmaf(D.x, hv1, fmaf(F.x, hv2, fmaf(H.x, hv3, acc[4]))));
        acc[5] = fmaf(B.y, hv0, fmaf(D.y, hv1, fmaf(F.y, hv2, fmaf(H.y, hv3, acc[5]))));
        acc[6] = fmaf(B.z, hv0, fmaf(D.z, hv1, fmaf(F.z, hv2, fmaf(H.z, hv3, acc[6]))));
        acc[7] = fmaf(B.w, hv0, fmaf(D.w, hv1, fmaf(F.w, hv2, fmaf(H.w, hv3, acc[7]))));
    }
    for (; p < pe; ++p) {
        int o0 = vcol[p];
        float hv0 = __half2float(h[(size_t)o0 * EMB + lane]);
        const float4* q4 = reinterpret_cast<const float4*>(l2 + (size_t)p * 8);
        float4 A = q4[0], B = q4[1];
        acc[0] = fmaf(A.x, hv0, acc[0]); acc[1] = fmaf(A.y, hv0, acc[1]);
        acc[2] = fmaf(A.z, hv0, acc[2]); acc[3] = fmaf(A.w, hv0, acc[3]);
        acc[4] = fmaf(B.x, hv0, acc[4]); acc[5] = fmaf(B.y, hv0, acc[5]);
        acc[6] = fmaf(B.z, hv0, acc[6]); acc[7] = fmaf(B.w, hv0, acc[7]);
    }
    if (s == 0) {
        float a = acc[0] + acc[1] + acc[2] + acc[3] +
                  acc[4] + acc[5] + acc[6] + acc[7];
        Abuf0[lane] = a;
        return;
    }
    Abuf0[(size_t)s * EMB + lane] = acc[0];
    if (pb == pe) return;
    int hq = lane >> 4, c = lane & 15;
#pragma unroll
    for (int rr = 1; rr < 8; ++rr) {
        int k = s * rr;
        int rp = k / NN;
        int n  = k - rp * NN;
        float v = 0.f;
#pragma unroll
        for (int hh = 0; hh < 16; ++hh) {
            float av = __shfl(acc[rr], hq * 16 + hh, 64);
            v = fmaf(av, w2[((rp * EMB) + (hq * 16 + hh)) * NCLS + c], v);
        }
        v += __shfl_xor(v, 16, 64);
        v += __shfl_xor(v, 32, 64);
        if (lane < 16) atomicAdd(&out[(size_t)n * NCLS + lane], v * sc[rr]);
    }
}

// ---------------- reduce Abuf0 + rs0part -> k=0 logits contribution ----------------
__global__ __launch_bounds__(256) void k_redA(
    const float* __restrict__ Abuf0, const float* __restrict__ rs0part,
    const float* __restrict__ w2, float* __restrict__ out)
{
    __shared__ float red[256];
    __shared__ float part[64];
    __shared__ float irs0s;
    float sv = 0.f;
    for (int i = threadIdx.x; i < NN; i += 256) sv += rs0part[i];
    red[threadIdx.x] = sv;
    __syncthreads();
    for (int off = 128; off > 0; off >>= 1) {
        if (threadIdx.x < off) red[threadIdx.x] += red[threadIdx.x + off];
        __syncthreads();
    }
    if (threadIdx.x == 0) irs0s = 1.0f / fmaxf(red[0], 1e-6f);
    __syncthreads();
    float irs0 = irs0s;
    int lane = threadIdx.x & 63, w = threadIdx.x >> 6;
    float sum = 0.f;
    for (int ss = blockIdx.x + 64 * w; ss < NN; ss += 256)
        sum += Abuf0[(size_t)ss * EMB + lane];
    red[threadIdx.x] = sum;
    __syncthreads();
    if (threadIdx.x < 64) {
        part[threadIdx.x] = red[threadIdx.x] + red[threadIdx.x + 64] +
                            red[threadIdx.x + 128] + red[threadIdx.x + 192];
    }
    __syncthreads();
    if (threadIdx.x < 64) {
        int hq = threadIdx.x >> 4, c = threadIdx.x & 15;
        float v = 0.f;
#pragma unroll
        for (int hh = 0; hh < 16; ++hh) {
            int hd = hq * 16 + hh;
            v = fmaf(part[hd], w2[hd * NCLS + c], v);
        }
        v += __shfl_xor(v, 16, 64);
        v += __shfl_xor(v, 32, 64);
        if (threadIdx.x < 16) atomicAdd(&out[c], v * irs0);
    }
}

extern "C" void kernel_launch(void* const* d_in, const int* in_sizes, int n_in,
                              void* d_out, int out_size, void* d_ws, size_t ws_size,
                              hipStream_t stream)
{
    const float* rm    = (const float*)d_in[0];
    const int*   hrow  = (const int*)d_in[1];   // sorted source nodes
    const int*   vcol  = (const int*)d_in[4];   // object nodes
    const float* W1    = (const float*)d_in[5];
    const float* b1    = (const float*)d_in[6];
    const float* W2    = (const float*)d_in[7];
    const float* b2    = (const float*)d_in[8];
    const float* w1    = (const float*)d_in[9];
    const float* w2    = (const float*)d_in[10];
    const float* bias1 = (const float*)d_in[11];
    const float* bias2 = (const float*)d_in[12];
    float* out = (float*)d_out;

    float* ws = (float*)d_ws;
    float*  l1      = ws;                       // [0, 2.00M)
    float*  l2      = ws + 2000000;             // [2.00M, 4.00M)
    int*    rowptr  = (int*)(ws + 4000000);     // 20,001 ints [4.000M, 4.021M)
    int*    cnt     = (int*)(ws + 4030000);     // 20,000 ints [4.03M, 4.05M)
    float*  colsum  = ws + 4100000;             // 160,000 (raw; divided in k_hacc)
    float*  rowsum  = ws + 4260000;             // 140,000 (raw; rcp'd in k_l2out)
    float*  h_acc   = ws + 4400000;             // 1.28M fp32 [4.40M, 5.68M)
    __half* h       = (__half*)(ws + 5680000);  // 1.28M halfs [5.68M, 6.32M)
    int*    cstart  = (int*)(ws + 6400000);     // 20,001
    int*    cnt2    = cstart + 20001;           // 20,000
    int*    cscidx  = cnt2 + 20000;             // 250,000 (ends ~6.69M)
    // Abuf0/rs0part overlay l1 (l1 dead after k_hacc)
    float*  Abuf0   = ws;                       // 1.28M
    float*  rs0part = ws + 1280000;             // 20,000

    // single memset: cnt + gap + colsum + rowsum + h_acc  [4.03M, 5.68M)
    hipMemsetAsync(cnt, 0, (size_t)(5680000 - 4030000) * sizeof(float), stream);

    k_gemv   <<<GEMVB + RPB + HIB + OIB, 256, 0, stream>>>(rm, W1, b1, W2, b2, l1, l2,
                                                           hrow, rowptr, vcol, cnt, out, bias2);
    k_scan   <<<1, 1024, 0, stream>>>(cnt, cstart, cnt2);
    k_pos    <<<(NT + 255) / 256, 256, 0, stream>>>(vcol, cnt2, cscidx);
    k_colsum <<<NN / 4 + REDB, 256, 0, stream>>>(l1, cstart, cscidx, colsum);
    k_hacc   <<<(NN * 64) / 256, 256, 0, stream>>>(l1, colsum, cstart, cscidx, hrow, w1, h_acc);
    k_h      <<<(NN * 64) / 256, 256, 0, stream>>>(h_acc, l2, rowptr, bias1, h, rowsum, rs0part);
    k_l2out  <<<(NN * 64) / 256, 256, 0, stream>>>(l2, rowptr, vcol, h, rowsum, w2, out, Abuf0);
    k_redA   <<<64, 256, 0, stream>>>(Abuf0, rs0part, w2, out);
}

// Round 18
// 233.377 us; speedup vs baseline: 1.0942x; 1.0942x over previous
//
#include <hip/hip_runtime.h>
#include <hip/hip_fp16.h>

#define NT      250000
#define NN      20000
#define RP      8
#define EMB     64
#define NCLS    16
#define NRELS   64
#define REDB    64
#define KMAX    140000    // max segment id + 1 (19999*7 = 139993)
#define GEMVB   977       // blocks for gemv part
#define RPB     79        // blocks for rowptr part
#define HIB     977       // blocks for hist part
#define OIB     1250      // blocks for out=bias2 init (1250*256 = 320000 exactly)

// ---------------- A (fused): GEMV + softmax | rowptr | histogram | out-init ----------------
__global__ __launch_bounds__(256) void k_gemv(
    const float* __restrict__ rm,
    const float* __restrict__ W1, const float* __restrict__ b1,
    const float* __restrict__ W2, const float* __restrict__ b2,
    float* __restrict__ l1, float* __restrict__ l2,
    const int* __restrict__ hrow, int* __restrict__ rowptr,
    const int* __restrict__ vcol, int* __restrict__ cnt,
    float* __restrict__ out, const float* __restrict__ bias2)
{
    __shared__ float tile[256 * 20];
    int bid = blockIdx.x;
    if (bid >= GEMVB) {
        int b = bid - GEMVB;
        if (b < RPB) {                    // CSR offsets via binary search
            int i = b * 256 + threadIdx.x;
            if (i > NN) return;
            int lo = 0, hi = NT;
            while (lo < hi) { int mid = (lo + hi) >> 1; if (hrow[mid] < i) lo = mid + 1; else hi = mid; }
            rowptr[i] = lo;
        } else if (b < RPB + HIB) {       // vcol histogram
            int p = (b - RPB) * 256 + threadIdx.x;
            if (p < NT) atomicAdd(&cnt[vcol[p]], 1);
        } else {                          // out = bias2 broadcast
            int i = (b - RPB - HIB) * 256 + threadIdx.x;
            if (i < NN * NCLS) out[i] = bias2[i & (NCLS - 1)];
        }
        return;
    }
    int t = threadIdx.x;
    int base = bid * 256;
    float a1[8], a2[8];
#pragma unroll
    for (int r = 0; r < 8; ++r) { a1[r] = b1[r]; a2[r] = b2[r]; }

#pragma unroll 1
    for (int kc = 0; kc < 4; ++kc) {
        __syncthreads();
#pragma unroll
        for (int q = 0; q < 4; ++q) {
            int i = q * 256 + t;
            int pl = i >> 2, j4 = i & 3;
            int p = base + pl;
            float4 v = make_float4(0.f, 0.f, 0.f, 0.f);
            if (p < NT) v = reinterpret_cast<const float4*>(rm)[(size_t)p * 16 + kc * 4 + j4];
            *reinterpret_cast<float4*>(&tile[pl * 20 + j4 * 4]) = v;
        }
        __syncthreads();
        float xr[16];
#pragma unroll
        for (int j4 = 0; j4 < 4; ++j4) {
            float4 v = *reinterpret_cast<const float4*>(&tile[t * 20 + j4 * 4]);
            xr[j4 * 4 + 0] = v.x; xr[j4 * 4 + 1] = v.y;
            xr[j4 * 4 + 2] = v.z; xr[j4 * 4 + 3] = v.w;
        }
#pragma unroll
        for (int kk = 0; kk < 16; ++kk) {
            float x = xr[kk];
            int k = kc * 16 + kk;
#pragma unroll
            for (int r = 0; r < 8; ++r) {
                a1[r] = fmaf(x, W1[k * 8 + r], a1[r]);
                a2[r] = fmaf(x, W2[k * 8 + r], a2[r]);
            }
        }
    }
    int p = base + t;
    if (p >= NT) return;
    float mx = a2[0];
#pragma unroll
    for (int r = 1; r < 8; ++r) mx = fmaxf(mx, a2[r]);
    float sm = 0.f;
#pragma unroll
    for (int r = 0; r < 8; ++r) { a2[r] = __expf(a2[r] - mx); sm += a2[r]; }
    float inv = 1.0f / sm;
#pragma unroll
    for (int r = 0; r < 8; ++r) a2[r] *= inv;
    float4* o1 = reinterpret_cast<float4*>(l1 + (size_t)p * 8);
    float4* o2 = reinterpret_cast<float4*>(l2 + (size_t)p * 8);
    o1[0] = make_float4(a1[0], a1[1], a1[2], a1[3]);
    o1[1] = make_float4(a1[4], a1[5], a1[6], a1[7]);
    o2[0] = make_float4(a2[0], a2[1], a2[2], a2[3]);
    o2[1] = make_float4(a2[4], a2[5], a2[6], a2[7]);
}

__global__ __launch_bounds__(1024) void k_scan(
    const int* __restrict__ cnt, int* __restrict__ cstart, int* __restrict__ cnt2)
{
    __shared__ int part[1024];
    int t = threadIdx.x;
    int base = t * 20;
    int local[20];
    int s = 0;
#pragma unroll
    for (int i = 0; i < 20; ++i) {
        int idx = base + i;
        int c = (idx < NN) ? cnt[idx] : 0;
        local[i] = s;
        s += c;
    }
    part[t] = s;
    __syncthreads();
    for (int off = 1; off < 1024; off <<= 1) {
        int v = (t >= off) ? part[t - off] : 0;
        __syncthreads();
        part[t] += v;
        __syncthreads();
    }
    int ebase = t ? part[t - 1] : 0;
#pragma unroll
    for (int i = 0; i < 20; ++i) {
        int idx = base + i;
        if (idx < NN) { cstart[idx] = ebase + local[i]; cnt2[idx] = ebase + local[i]; }
    }
    if (t == 1023) cstart[NN] = part[1023];
}

__global__ __launch_bounds__(256) void k_pos(
    const int* __restrict__ vcol, int* __restrict__ cnt2, int* __restrict__ cscidx)
{
    int p = blockIdx.x * blockDim.x + threadIdx.x;
    if (p >= NT) return;
    int o = vcol[p];
    int slot = atomicAdd(&cnt2[o], 1);
    cscidx[slot] = p;
}

// ---------------- colsum: wave per o (r=1..7) + REDB streaming blocks (r=0 -> colsum[0]) ----------------
__global__ __launch_bounds__(256) void k_colsum(
    const float* __restrict__ l1, const int* __restrict__ cstart,
    const int* __restrict__ cscidx, float* __restrict__ colsum)
{
    int bid = blockIdx.x;
    if (bid < NN / 4) {
        int o = bid * 4 + (threadIdx.x >> 6);
        int lane = threadIdx.x & 63;
        int qb = cstart[o], qe = cstart[o + 1];
        if (qb == qe) return;
        int j = lane >> 3, r = lane & 7;
        float sum = 0.f;
        for (int q0 = qb; q0 < qe; q0 += 8) {
            int q = q0 + j;
            if (q < qe) sum += l1[(size_t)cscidx[q] * 8 + r];
        }
        sum += __shfl_xor(sum, 8, 64);
        sum += __shfl_xor(sum, 16, 64);
        sum += __shfl_xor(sum, 32, 64);   // lanes 0..7 hold per-r totals
        if (lane >= 1 && lane < 8) atomicAdd(&colsum[o * lane], sum);
    } else {
        int b2 = bid - NN / 4;
        float s = 0.f;
        for (int i = b2 * 256 + threadIdx.x; i < NT; i += REDB * 256) s += l1[(size_t)i * 8];
        __shared__ float red[256];
        red[threadIdx.x] = s;
        __syncthreads();
        for (int off = 128; off > 0; off >>= 1) {
            if (threadIdx.x < off) red[threadIdx.x] += red[threadIdx.x + off];
            __syncthreads();
        }
        if (threadIdx.x == 0) atomicAdd(&colsum[0], red[0]);
    }
}

// ---------------- C1: per-object contributions (rcpf-folded division; unroll-4 gathers) ----------------
__global__ __launch_bounds__(256) void k_contrib(
    const float* __restrict__ l1, const float* __restrict__ colsum,
    const int* __restrict__ cstart, const int* __restrict__ cscidx,
    const float* __restrict__ w1, __half* __restrict__ contrib)
{
    int o = (int)((blockIdx.x * blockDim.x + threadIdx.x) >> 6);
    int lane = threadIdx.x & 63;
    if (o >= NN) return;
    int qb = cstart[o], qe = cstart[o + 1];
    if (qb == qe) return;
    float y[8];
    y[0] = w1[lane] * __builtin_amdgcn_rcpf(colsum[0]);
#pragma unroll
    for (int r = 1; r < 8; ++r) {
        int seg = o * r;
        y[r] = w1[(size_t)seg * EMB + lane] * __builtin_amdgcn_rcpf(colsum[seg]);
    }
    int q = qb;
    for (; q + 3 < qe; q += 4) {          // four l1 gathers in flight
        int p0 = cscidx[q], p1 = cscidx[q + 1], p2 = cscidx[q + 2], p3 = cscidx[q + 3];
        const float4* a4 = reinterpret_cast<const float4*>(l1 + (size_t)p0 * 8);
        const float4* b4 = reinterpret_cast<const float4*>(l1 + (size_t)p1 * 8);
        const float4* c4 = reinterpret_cast<const float4*>(l1 + (size_t)p2 * 8);
        const float4* d4 = reinterpret_cast<const float4*>(l1 + (size_t)p3 * 8);
        float4 A = a4[0], B = a4[1], C = b4[0], D = b4[1];
        float4 E = c4[0], F = c4[1], G = d4[0], H = d4[1];
        float v0 = A.x * y[0];
        v0 = fmaf(A.y, y[1], v0); v0 = fmaf(A.z, y[2], v0); v0 = fmaf(A.w, y[3], v0);
        v0 = fmaf(B.x, y[4], v0); v0 = fmaf(B.y, y[5], v0);
        v0 = fmaf(B.z, y[6], v0); v0 = fmaf(B.w, y[7], v0);
        float v1 = C.x * y[0];
        v1 = fmaf(C.y, y[1], v1); v1 = fmaf(C.z, y[2], v1); v1 = fmaf(C.w, y[3], v1);
        v1 = fmaf(D.x, y[4], v1); v1 = fmaf(D.y, y[5], v1);
        v1 = fmaf(D.z, y[6], v1); v1 = fmaf(D.w, y[7], v1);
        float v2 = E.x * y[0];
        v2 = fmaf(E.y, y[1], v2); v2 = fmaf(E.z, y[2], v2); v2 = fmaf(E.w, y[3], v2);
        v2 = fmaf(F.x, y[4], v2); v2 = fmaf(F.y, y[5], v2);
        v2 = fmaf(F.z, y[6], v2); v2 = fmaf(F.w, y[7], v2);
        float v3 = G.x * y[0];
        v3 = fmaf(G.y, y[1], v3); v3 = fmaf(G.z, y[2], v3); v3 = fmaf(G.w, y[3], v3);
        v3 = fmaf(H.x, y[4], v3); v3 = fmaf(H.y, y[5], v3);
        v3 = fmaf(H.z, y[6], v3); v3 = fmaf(H.w, y[7], v3);
        contrib[(size_t)p0 * EMB + lane] = __float2half(v0);
        contrib[(size_t)p1 * EMB + lane] = __float2half(v1);
        contrib[(size_t)p2 * EMB + lane] = __float2half(v2);
        contrib[(size_t)p3 * EMB + lane] = __float2half(v3);
    }
    for (; q < qe; ++q) {
        int p0 = cscidx[q];
        const float4* a4 = reinterpret_cast<const float4*>(l1 + (size_t)p0 * 8);
        float4 A = a4[0], B = a4[1];
        float v0 = A.x * y[0];
        v0 = fmaf(A.y, y[1], v0); v0 = fmaf(A.z, y[2], v0); v0 = fmaf(A.w, y[3], v0);
        v0 = fmaf(B.x, y[4], v0); v0 = fmaf(B.y, y[5], v0);
        v0 = fmaf(B.z, y[6], v0); v0 = fmaf(B.w, y[7], v0);
        contrib[(size_t)p0 * EMB + lane] = __float2half(v0);
    }
}

// ---------------- C2 (fused): h = relu(bias + sum contrib) + rowsum pre-pass ----------------
__global__ __launch_bounds__(256) void k_h(
    const __half* __restrict__ contrib, const float* __restrict__ l2,
    const int* __restrict__ rowptr, const float* __restrict__ bias1,
    __half* __restrict__ h, float* __restrict__ rowsum, float* __restrict__ rs0part)
{
    int s = (int)((blockIdx.x * blockDim.x + threadIdx.x) >> 6);
    int lane = threadIdx.x & 63;
    if (s >= NN) return;
    int pb = rowptr[s], pe = rowptr[s + 1];
    float acc = 0.f;
    for (int p = pb; p < pe; ++p)
        acc += __half2float(contrib[(size_t)p * EMB + lane]);
    h[(size_t)s * EMB + lane] = __float2half(fmaxf(acc + bias1[lane], 0.f));

    float psum = 0.f;
    for (int p0 = pb + (lane >> 3); p0 < pe; p0 += 8)
        psum += l2[(size_t)p0 * 8 + (lane & 7)];
    psum += __shfl_xor(psum, 8, 64);
    psum += __shfl_xor(psum, 16, 64);
    psum += __shfl_xor(psum, 32, 64);
    if (s == 0) {
        float tt = psum;
        tt += __shfl_xor(tt, 1, 64);
        tt += __shfl_xor(tt, 2, 64);
        tt += __shfl_xor(tt, 4, 64);
        if (lane == 0) rs0part[0] = tt;
    } else {
        if (lane == 0) rs0part[s] = psum;
        else if (lane < 8) atomicAdd(&rowsum[s * lane], psum);
    }
}

// ---------------- D+E fused: single wave per s, unroll-4, fast-rcp rowsum divides ----------------
__global__ __launch_bounds__(256) void k_l2out(
    const float* __restrict__ l2, const int* __restrict__ rowptr,
    const int* __restrict__ vcol, const __half* __restrict__ h,
    const float* __restrict__ rowsum, const float* __restrict__ w2,
    float* __restrict__ out, float* __restrict__ Abuf0)
{
    int s = (int)((blockIdx.x * blockDim.x + threadIdx.x) >> 6);
    int lane = threadIdx.x & 63;
    if (s >= NN) return;
    int pb = rowptr[s], pe = rowptr[s + 1];
    float sc[8];
#pragma unroll
    for (int rr = 1; rr < 8; ++rr)
        sc[rr] = (s > 0) ? __builtin_amdgcn_rcpf(fmaxf(rowsum[s * rr], 1e-6f)) : 0.f;
    float acc[8];
#pragma unroll
    for (int r = 0; r < 8; ++r) acc[r] = 0.f;
    int p = pb;
    for (; p + 3 < pe; p += 4) {            // four h gathers in flight
        int o0 = vcol[p], o1 = vcol[p + 1], o2 = vcol[p + 2], o3 = vcol[p + 3];
        float hv0 = __half2float(h[(size_t)o0 * EMB + lane]);
        float hv1 = __half2float(h[(size_t)o1 * EMB + lane]);
        float hv2 = __half2float(h[(size_t)o2 * EMB + lane]);
        float hv3 = __half2float(h[(size_t)o3 * EMB + lane]);
        const float4* q4 = reinterpret_cast<const float4*>(l2 + (size_t)p * 8);
        float4 A = q4[0], B = q4[1], C = q4[2], D = q4[3];
        float4 E = q4[4], F = q4[5], G = q4[6], H = q4[7];
        acc[0] = fmaf(A.x, hv0, fmaf(C.x, hv1, fmaf(E.x, hv2, fmaf(G.x, hv3, acc[0]))));
        acc[1] = fmaf(A.y, hv0, fmaf(C.y, hv1, fmaf(E.y, hv2, fmaf(G.y, hv3, acc[1]))));
        acc[2] = fmaf(A.z, hv0, fmaf(C.z, hv1, fmaf(E.z, hv2, fmaf(G.z, hv3, acc[2]))));
        acc[3] = fmaf(A.w, hv0, fmaf(C.w, hv1, fmaf(E.w, hv2, fmaf(G.w, hv3, acc[3]))));
        acc[4] = fmaf(B.x, hv0, fmaf(D.x, hv1, fmaf(F.x, hv2, fmaf(H.x, hv3, acc[4]))));
        acc[5] = fmaf(B.y, hv0, fmaf(D.y, hv1, fmaf(F.y, hv2, fmaf(H.y, hv3, acc[5]))));
        acc[6] = fmaf(B.z, hv0, fmaf(D.z, hv1, fmaf(F.z, hv2, fmaf(H.z, hv3, acc[6]))));
        acc[7] = fmaf(B.w, hv0, fmaf(D.w, hv1, fmaf(F.w, hv2, fmaf(H.w, hv3, acc[7]))));
    }
    for (; p < pe; ++p) {
        int o0 = vcol[p];
        float hv0 = __half2float(h[(size_t)o0 * EMB + lane]);
        const float4* q4 = reinterpret_cast<const float4*>(l2 + (size_t)p * 8);
        float4 A = q4[0], B = q4[1];
        acc[0] = fmaf(A.x, hv0, acc[0]); acc[1] = fmaf(A.y, hv0, acc[1]);
        acc[2] = fmaf(A.z, hv0, acc[2]); acc[3] = fmaf(A.w, hv0, acc[3]);
        acc[4] = fmaf(B.x, hv0, acc[4]); acc[5] = fmaf(B.y, hv0, acc[5]);
        acc[6] = fmaf(B.z, hv0, acc[6]); acc[7] = fmaf(B.w, hv0, acc[7]);
    }
    if (s == 0) {
        float a = acc[0] + acc[1] + acc[2] + acc[3] +
                  acc[4] + acc[5] + acc[6] + acc[7];
        Abuf0[lane] = a;
        return;
    }
    Abuf0[(size_t)s * EMB + lane] = acc[0];
    if (pb == pe) return;
    int hq = lane >> 4, c = lane & 15;
#pragma unroll
    for (int rr = 1; rr < 8; ++rr) {
        int k = s * rr;
        int rp = k / NN;
        int n  = k - rp * NN;
        float v = 0.f;
#pragma unroll
        for (int hh = 0; hh < 16; ++hh) {
            float av = __shfl(acc[rr], hq * 16 + hh, 64);
            v = fmaf(av, w2[((rp * EMB) + (hq * 16 + hh)) * NCLS + c], v);
        }
        v += __shfl_xor(v, 16, 64);
        v += __shfl_xor(v, 32, 64);
        if (lane < 16) atomicAdd(&out[(size_t)n * NCLS + lane], v * sc[rr]);
    }
}

// ---------------- reduce Abuf0 + rs0part -> k=0 logits contribution ----------------
__global__ __launch_bounds__(256) void k_redA(
    const float* __restrict__ Abuf0, const float* __restrict__ rs0part,
    const float* __restrict__ w2, float* __restrict__ out)
{
    __shared__ float red[256];
    __shared__ float part[64];
    __shared__ float irs0s;
    float sv = 0.f;
    for (int i = threadIdx.x; i < NN; i += 256) sv += rs0part[i];
    red[threadIdx.x] = sv;
    __syncthreads();
    for (int off = 128; off > 0; off >>= 1) {
        if (threadIdx.x < off) red[threadIdx.x] += red[threadIdx.x + off];
        __syncthreads();
    }
    if (threadIdx.x == 0) irs0s = 1.0f / fmaxf(red[0], 1e-6f);
    __syncthreads();
    float irs0 = irs0s;
    int lane = threadIdx.x & 63, w = threadIdx.x >> 6;
    float sum = 0.f;
    for (int ss = blockIdx.x + 64 * w; ss < NN; ss += 256)
        sum += Abuf0[(size_t)ss * EMB + lane];
    red[threadIdx.x] = sum;
    __syncthreads();
    if (threadIdx.x < 64) {
        part[threadIdx.x] = red[threadIdx.x] + red[threadIdx.x + 64] +
                            red[threadIdx.x + 128] + red[threadIdx.x + 192];
    }
    __syncthreads();
    if (threadIdx.x < 64) {
        int hq = threadIdx.x >> 4, c = threadIdx.x & 15;
        float v = 0.f;
#pragma unroll
        for (int hh = 0; hh < 16; ++hh) {
            int hd = hq * 16 + hh;
            v = fmaf(part[hd], w2[hd * NCLS + c], v);
        }
        v += __shfl_xor(v, 16, 64);
        v += __shfl_xor(v, 32, 64);
        if (threadIdx.x < 16) atomicAdd(&out[c], v * irs0);
    }
}

extern "C" void kernel_launch(void* const* d_in, const int* in_sizes, int n_in,
                              void* d_out, int out_size, void* d_ws, size_t ws_size,
                              hipStream_t stream)
{
    const float* rm    = (const float*)d_in[0];
    const int*   hrow  = (const int*)d_in[1];   // sorted source nodes
    const int*   vcol  = (const int*)d_in[4];   // object nodes
    const float* W1    = (const float*)d_in[5];
    const float* b1    = (const float*)d_in[6];
    const float* W2    = (const float*)d_in[7];
    const float* b2    = (const float*)d_in[8];
    const float* w1    = (const float*)d_in[9];
    const float* w2    = (const float*)d_in[10];
    const float* bias1 = (const float*)d_in[11];
    const float* bias2 = (const float*)d_in[12];
    float* out = (float*)d_out;

    float* ws = (float*)d_ws;
    float*  l1      = ws;                       // [0, 2.00M)
    float*  l2      = ws + 2000000;             // [2.00M, 4.00M)
    int*    rowptr  = (int*)(ws + 4000000);     // 20,001 ints
    int*    cnt     = (int*)(ws + 4030000);     // 20,000 ints [4.03M, 4.05M)
    float*  colsum  = ws + 4100000;             // 160,000 (raw; rcp'd in k_contrib)
    float*  rowsum  = ws + 4260000;             // 140,000 (raw; rcp'd in k_l2out) — ends 4.40M
    __half* h       = (__half*)(ws + 4400000);  // 1.28M halfs [4.40M, 5.04M)
    int*    cstart  = (int*)(ws + 5040000);     // 20,001
    int*    cnt2    = cstart + 20001;           // 20,000
    int*    cscidx  = cnt2 + 20000;             // 250,000 (ends 5.35M)
    __half* contrib = (__half*)(ws + 5600000);  // 16M halfs [5.60M, 13.60M)
    // Abuf0/rs0part overlay l1 (l1 dead after k_contrib)
    float*  Abuf0   = ws;                       // 1.28M
    float*  rs0part = ws + 1280000;             // 20,000

    // single memset: cnt + gap + colsum + rowsum  [4.03M, 4.40M)
    hipMemsetAsync(cnt, 0, (size_t)(4400000 - 4030000) * sizeof(float), stream);

    k_gemv   <<<GEMVB + RPB + HIB + OIB, 256, 0, stream>>>(rm, W1, b1, W2, b2, l1, l2,
                                                           hrow, rowptr, vcol, cnt, out, bias2);
    k_scan   <<<1, 1024, 0, stream>>>(cnt, cstart, cnt2);
    k_pos    <<<(NT + 255) / 256, 256, 0, stream>>>(vcol, cnt2, cscidx);
    k_colsum <<<NN / 4 + REDB, 256, 0, stream>>>(l1, cstart, cscidx, colsum);
    k_contrib<<<(NN * 64) / 256, 256, 0, stream>>>(l1, colsum, cstart, cscidx, w1, contrib);
    k_h      <<<(NN * 64) / 256, 256, 0, stream>>>(contrib, l2, rowptr, bias1, h, rowsum, rs0part);
    k_l2out  <<<(NN * 64) / 256, 256, 0, stream>>>(l2, rowptr, vcol, h, rowsum, w2, out, Abuf0);
    k_redA   <<<64, 256, 0, stream>>>(Abuf0, rs0part, w2, out);
}